// Round 17
// baseline (138.981 us; speedup 1.0000x reference)
//
#include <hip/hip_runtime.h>
#include <cstdint>
#include <cstddef>

#define THREADS 256
#define NB 8   // partial-sum blocks per group

typedef float f32x4 __attribute__((ext_vector_type(4)));
typedef __bf16 bf16x8 __attribute__((ext_vector_type(8)));
typedef __bf16 bf16x4 __attribute__((ext_vector_type(4)));

// ---------- async global->LDS, 16B per lane, wave-uniform LDS base ----------
__device__ __forceinline__ void gload_lds16(const void* g, void* l) {
    auto gp = (const __attribute__((address_space(1))) unsigned int*)(unsigned long long)(uintptr_t)g;
    auto lp = (__attribute__((address_space(3))) unsigned int*)(unsigned int)(uintptr_t)l;
    __builtin_amdgcn_global_load_lds(gp, lp, 16, 0, 0);
}

// ---------- exact-GELU with fast erf (A&S 7.1.26, |err|<=1.5e-7) -----------
// Validated R12-R16 (absmax 0.5). ~15 VALU ops vs libm erff ~84.
__device__ __forceinline__ float gelu_fast(float f) {
    const float z = f * 0.70710678118654752f;
    const float az = fabsf(z);
    const float t = __builtin_amdgcn_rcpf(fmaf(0.3275911f, az, 1.0f));
    float poly = fmaf(1.061405429f, t, -1.453152027f);
    poly = fmaf(poly, t, 1.421413741f);
    poly = fmaf(poly, t, -0.284496736f);
    poly = fmaf(poly, t, 0.254829592f);
    poly *= t;
    const float e = __builtin_amdgcn_exp2f(-az * az * 1.44269504088896f);
    float erfv = fmaf(-poly, e, 1.0f);
    erfv = copysignf(erfv, z);
    return 0.5f * f * (1.0f + erfv);
}

// ---------- prep A: W partial sums (80 blks) + x->bf16 cvt (7680 blks) ------
__global__ void prep_a(const float* __restrict__ x, __bf16* __restrict__ xb,
                       const float* __restrict__ W1, const float* __restrict__ W2,
                       float* __restrict__ partials, int epg1, int epg2,
                       unsigned int* __restrict__ gzero) {
    const int blk = blockIdx.x, tid = threadIdx.x;
    if (blk < 80) {
        const int y = blk >> 3, b = blk & 7;
        if (blk == 0 && tid < 16) gzero[tid] = 0u;
        const int epg = (y < 5) ? epg1 : epg2;
        const float* Wg = (y < 5) ? (W1 + (size_t)y * epg1)
                                  : (W2 + (size_t)(y - 5) * epg2);
        const int chunk4 = epg / (4 * NB);
        const float* base = Wg + (size_t)b * chunk4 * 4;
        float s = 0.f;
        for (int i = tid; i < chunk4; i += THREADS) {
            f32x4 v = *reinterpret_cast<const f32x4*>(base + 4 * (size_t)i);
            s += (v[0] + v[1]) + (v[2] + v[3]);
        }
        __shared__ float red[THREADS];
        red[tid] = s;
        __syncthreads();
        for (int off = THREADS / 2; off > 0; off >>= 1) {
            if (tid < off) red[tid] += red[tid + off];
            __syncthreads();
        }
        if (tid == 0) partials[y * NB + b] = red[0];
        return;
    }
    const int i = (blk - 80) * THREADS + tid;
    f32x4 v = *reinterpret_cast<const f32x4*>(x + 4 * (size_t)i);
    bf16x4 o;
    o[0] = (__bf16)v[0]; o[1] = (__bf16)v[1];
    o[2] = (__bf16)v[2]; o[3] = (__bf16)v[3];
    *reinterpret_cast<bf16x4*>(xb + 4 * (size_t)i) = o;
}

// ---------- prep B: binarize W1/W2 chunks + tail zero (82 blocks) -----------
__global__ void prep_b(const float* __restrict__ W1, __bf16* __restrict__ W1b,
                       const float* __restrict__ W2, __bf16* __restrict__ W2b,
                       const float* __restrict__ psums,
                       int epg1, int tail1, int epg2, int tail2) {
    int r = blockIdx.x;
    const int tid = threadIdx.x;
    const float* W; __bf16* Wb; const float* ps; int epg, tail;
    if (r <= 40) { W = W1; Wb = W1b; ps = psums;      epg = epg1; tail = tail1; }
    else { r -= 41; W = W2; Wb = W2b; ps = psums + 40; epg = epg2; tail = tail2; }
    if (r == 40) {
        __bf16* og = Wb + (size_t)5 * epg;
        for (int i = tid; i < tail; i += THREADS) og[i] = (__bf16)0.f;
        return;
    }
    const int g = r >> 3, b = r & 7;
    float total = 0.f;
#pragma unroll
    for (int j = 0; j < NB; ++j) total += ps[g * NB + j];
    const float mean = total / (float)epg;
    const int chunk4 = epg / (4 * NB);
    const size_t off0 = (size_t)g * epg + (size_t)b * chunk4 * 4;
    const float* base = W + off0;
    __bf16* ob = Wb + off0;
    for (int i = tid; i < chunk4; i += THREADS) {
        f32x4 v = *reinterpret_cast<const f32x4*>(base + 4 * (size_t)i);
        bf16x4 o;
#pragma unroll
        for (int j = 0; j < 4; ++j) {
            const float z = v[j] - mean;
            o[j] = (__bf16)((z > 0.f) ? 1.f : ((z < 0.f) ? -1.f : 0.f));
        }
        *reinterpret_cast<bf16x4*>(ob + 4 * (size_t)i) = o;
    }
}

// ========== 3-buffer deep-prefetch GEMM: Y[m,n] = A[m,:]*Bw[n,:] + bias[n] ==
// BM=256, BN=128, BK=64, 8 waves (2Mx4N). THREE LDS buffers (48KB x 3 =
// 144KB): STAGE(t+2) issued at top of tile t -> each tile's loads get ~2
// compute phases to cover HBM latency (R12's 2-buffer gave only ~320cyc vs
// ~900cyc HBM). Boundary wait is COUNTED vmcnt(6) (t+2's 6 loads stay in
// flight across the barrier) — never 0 in steady state (T4). Ledger: after
// STAGE(t+2), outstanding = {t+1:6, t+2:6}; vmcnt(6) => t+1 landed. Buffer
// (t+2)%3 disjoint from compute buffer t%3 and from t+1's; all waves sit
// between the same two barriers => race-free. Proven pieces kept: T2 XOR
// swizzle, XCD bijective swizzle, SWAPPED mfma(bfv,af) wide stores.
template<int OUT_BF16>
__global__ __launch_bounds__(512, 1)
void gemm_p3(const __bf16* __restrict__ A, const __bf16* __restrict__ Bw,
             const float* __restrict__ bias, void* __restrict__ outp,
             unsigned int* __restrict__ gmax, int M, int N, int K,
             int GN, int nwg) {
    constexpr int BM = 256, BN_ = 128, BK = 64, NF = 2;
    constexpr int ABYTES = BM * BK * 2;        // 32768
    constexpr int BBYTES = BN_ * BK * 2;       // 16384
    constexpr int BUF = ABYTES + BBYTES;       // 49152
    __shared__ __attribute__((aligned(16))) char lds[3 * BUF];   // 144 KB

    const int tid = threadIdx.x;
    const int wave = tid >> 6, lane = tid & 63;
    const int l15 = lane & 15, l4 = lane >> 4;
    const int wr = wave >> 2, wc = wave & 3;

    const int cpx = nwg >> 3;
    const int orig = (blockIdx.x & 7) * cpx + (blockIdx.x >> 3);
    const int bm = orig / GN, bn = orig % GN;

    const __bf16* Ab = A + (size_t)bm * BM * K;
    const __bf16* Bb = Bw + (size_t)bn * BN_ * K;
    const int NT = K / BK;

    f32x4 acc[8][NF];
#pragma unroll
    for (int m = 0; m < 8; ++m)
#pragma unroll
        for (int n = 0; n < NF; ++n)
            acc[m][n] = f32x4{0.f, 0.f, 0.f, 0.f};

    auto STAGE = [&](int t, int buf) {       // 6 loads/thread: A 4 + B 2
        const int k0 = t * BK;
        char* ab = lds + buf * BUF;
        char* bb = ab + ABYTES;
#pragma unroll
        for (int j = 0; j < 4; ++j) {
            const int q = j * 8192 + tid * 16;
            const int lr = q >> 7;
            const int s = ((q >> 4) & 7) ^ (lr & 7);
            gload_lds16(Ab + (size_t)lr * K + k0 + s * 8, ab + q);
        }
#pragma unroll
        for (int j = 0; j < 2; ++j) {
            const int q = j * 8192 + tid * 16;
            const int lr = q >> 7;
            const int s = ((q >> 4) & 7) ^ (lr & 7);
            gload_lds16(Bb + (size_t)lr * K + k0 + s * 8, bb + q);
        }
    };

    // prologue: tiles 0 and 1 in flight; wait for tile 0 only (counted).
    STAGE(0, 0);
    STAGE(1, 1);
    asm volatile("s_waitcnt vmcnt(6)" ::: "memory");
    __syncthreads();

    int cur = 0;
    for (int t = 0; t < NT; ++t) {
        const int nxt2 = (cur >= 1) ? cur - 1 : cur + 2;   // (cur+2)%3
        if (t + 2 < NT) STAGE(t + 2, nxt2);
        const char* ab = lds + cur * BUF;
        const char* bb = ab + ABYTES;
#pragma unroll
        for (int kk = 0; kk < 2; ++kk) {
            bf16x8 af[8], bfv[NF];
#pragma unroll
            for (int m = 0; m < 8; ++m) {
                const int r = wr * 128 + m * 16 + l15;
                const int sp = (kk * 4 + l4) ^ (r & 7);
                af[m] = *reinterpret_cast<const bf16x8*>(ab + r * 128 + sp * 16);
            }
#pragma unroll
            for (int n = 0; n < NF; ++n) {
                const int r = wc * 32 + n * 16 + l15;
                const int sp = (kk * 4 + l4) ^ (r & 7);
                bfv[n] = *reinterpret_cast<const bf16x8*>(bb + r * 128 + sp * 16);
            }
#pragma unroll
            for (int m = 0; m < 8; ++m)
#pragma unroll
                for (int n = 0; n < NF; ++n)
                    acc[m][n] = __builtin_amdgcn_mfma_f32_16x16x32_bf16(
                        bfv[n], af[m], acc[m][n], 0, 0, 0);   // SWAPPED
        }
        if (t + 2 < NT)      asm volatile("s_waitcnt vmcnt(6)" ::: "memory");
        else if (t + 1 < NT) asm volatile("s_waitcnt vmcnt(0)" ::: "memory");
        __syncthreads();
        cur = (cur == 2) ? 0 : cur + 1;
    }

    // epilogue (swapped): row = rowb+m*16+l15, col = colb+n*16+l4*4+r
    const int rowb = bm * BM + wr * 128;
    const int colb = bn * BN_ + wc * 32;
    float lmax = 0.f;
#pragma unroll
    for (int n = 0; n < NF; ++n) {
        const f32x4 bv = *reinterpret_cast<const f32x4*>(bias + colb + n * 16 + l4 * 4);
#pragma unroll
        for (int m = 0; m < 8; ++m) {
            const int row = rowb + m * 16 + l15;
            if (OUT_BF16) {
                bf16x4 o;
#pragma unroll
                for (int r = 0; r < 4; ++r) {
                    const float v = acc[m][n][r] + bv[r];
                    lmax = fmaxf(lmax, fabsf(v));
                    o[r] = (__bf16)v;
                }
                *reinterpret_cast<bf16x4*>(
                    &((__bf16*)outp)[(size_t)row * N + colb + n * 16 + l4 * 4]) = o;
            } else {
                f32x4 o;
#pragma unroll
                for (int r = 0; r < 4; ++r) {
                    o[r] = acc[m][n][r] + bv[r];
                    lmax = fmaxf(lmax, fabsf(o[r]));
                }
                *reinterpret_cast<f32x4*>(
                    &((float*)outp)[(size_t)row * N + colb + n * 16 + l4 * 4]) = o;
            }
        }
    }
#pragma unroll
    for (int off = 32; off > 0; off >>= 1)
        lmax = fmaxf(lmax, __shfl_down(lmax, off, 64));
    float* wredmax = (float*)lds;   // safe: all tile reads done
    if (lane == 0) wredmax[wave] = lmax;
    __syncthreads();
    if (tid == 0) {
        float bmax = wredmax[0];
#pragma unroll
        for (int w = 1; w < 8; ++w) bmax = fmaxf(bmax, wredmax[w]);
        atomicMax(gmax + (bm * BM) / 4096, __float_as_uint(bmax));
    }
}

// ---------- in-place absmax quantize + FAST exact-GELU, grid-stride ---------
__global__ void quant_gelu(__bf16* __restrict__ y, const unsigned int* __restrict__ gbits,
                           int perg8, int n8) {
    const int stride = gridDim.x * blockDim.x;
    for (int i = blockIdx.x * blockDim.x + threadIdx.x; i < n8; i += stride) {
        const int g = i / perg8;
        const float gamma = __uint_as_float(gbits[g]);
        const float s = 128.0f / (gamma + 1e-5f);
        bf16x8 v = *reinterpret_cast<const bf16x8*>(y + 8 * (size_t)i);
        bf16x8 o;
#pragma unroll
        for (int j = 0; j < 8; ++j) {
            float f = (float)v[j] * s;
            f = fminf(fmaxf(f, -128.0f + 1e-5f), 128.0f - 1e-5f);
            o[j] = (__bf16)gelu_fast(f);
        }
        *reinterpret_cast<bf16x8*>(y + 8 * (size_t)i) = o;
    }
}

// ---------- in-place absmax quantize of f32 output ----------
__global__ void final_scale(float* __restrict__ y, const unsigned int* __restrict__ gbits,
                            int perg4, int n4) {
    int i = blockIdx.x * blockDim.x + threadIdx.x;
    if (i >= n4) return;
    const int g = i / perg4;
    const float gamma = __uint_as_float(gbits[g]);
    const float s = 128.0f / (gamma + 1e-5f);
    f32x4 v = *reinterpret_cast<const f32x4*>(y + 4 * (size_t)i);
    f32x4 o;
#pragma unroll
    for (int j = 0; j < 4; ++j)
        o[j] = fminf(fmaxf(v[j] * s, -128.0f + 1e-5f), 128.0f - 1e-5f);
    *reinterpret_cast<f32x4*>(y + 4 * (size_t)i) = o;
}

extern "C" void kernel_launch(void* const* d_in, const int* in_sizes, int n_in,
                              void* d_out, int out_size, void* d_ws, size_t ws_size,
                              hipStream_t stream) {
    const float* x  = (const float*)d_in[0];   // (10,2048,384)
    const float* W1 = (const float*)d_in[1];   // (1536,384)
    const float* b1 = (const float*)d_in[2];   // (1536,)
    const float* W2 = (const float*)d_in[3];   // (384,1536)
    const float* b2 = (const float*)d_in[4];   // (384,)
    float* out = (float*)d_out;                // (10,2048,384) f32

    const int BB = 10, TT = 2048, C = 384, H = 1536;
    const int M = BB * TT;                     // 20480; act group = 4096 rows

    const int gs1 = H / 5;                     // 307
    const int gs2 = C / 5;                     // 76
    const int epg1 = gs1 * C;                  // 117888
    const int epg2 = gs2 * H;                  // 116736
    const int tail1 = (H - 5 * gs1) * C;       // 384
    const int tail2 = (C - 5 * gs2) * H;       // 6144

    const size_t szW1b = (size_t)H * C * 2;
    const size_t szW2b = (size_t)C * H * 2;
    const size_t szXb  = (size_t)M * C * 2;
    const size_t szY1  = (size_t)M * H * 2;

    char* p = (char*)d_ws;
    __bf16* W1b = (__bf16*)p; p += szW1b;
    __bf16* W2b = (__bf16*)p; p += szW2b;
    __bf16* xb  = (__bf16*)p; p += szXb;
    __bf16* y1  = (__bf16*)p; p += szY1;
    unsigned int* gamma = (unsigned int*)p; p += 64;
    float* psums = (float*)p; p += 2 * 5 * NB * 4;
    if ((size_t)(p - (char*)d_ws) > ws_size) return;

    // 1) W partial sums (80 blks, gamma zero) + x->bf16 cvt (7680 blks)
    prep_a<<<7760, THREADS, 0, stream>>>(x, xb, W1, W2, psums, epg1, epg2, gamma);

    // 2) binarize W1/W2 + tail zeroing
    prep_b<<<82, THREADS, 0, stream>>>(W1, W1b, W2, W2b, psums,
                                       epg1, tail1, epg2, tail2);

    // 3) GEMM1: 20480x1536x384, BM=256 BN=128 -> grid 80*12 = 960 (%8==0)
    gemm_p3<1><<<960, 512, 0, stream>>>(
        xb, W1b, b1, (void*)y1, gamma, M, H, C, H / 128, 960);

    // 4) quant+gelu (fast erf), grid-stride
    quant_gelu<<<2048, THREADS, 0, stream>>>(
        y1, gamma, (M / 5) * H / 8, M * H / 8);

    // 5) GEMM2: 20480x384x1536, grid 80*3 = 240 (%8==0)
    gemm_p3<0><<<240, 512, 0, stream>>>(
        y1, W2b, b2, (void*)out, gamma + 5, M, C, H, C / 128, 240);

    // 6) final scale+clip of output
    final_scale<<<(M * C / 4 + THREADS - 1) / THREADS, THREADS, 0, stream>>>(
        out, gamma + 5, (M / 5) * C / 4, M * C / 4);
}

// Round 18
// 130.797 us; speedup vs baseline: 1.0626x; 1.0626x over previous
//
#include <hip/hip_runtime.h>
#include <cstdint>
#include <cstddef>

#define THREADS 256
#define NB 8   // partial-sum blocks per group

typedef float f32x4 __attribute__((ext_vector_type(4)));
typedef __bf16 bf16x8 __attribute__((ext_vector_type(8)));
typedef __bf16 bf16x4 __attribute__((ext_vector_type(4)));

// ---------- async global->LDS, 16B per lane, wave-uniform LDS base ----------
__device__ __forceinline__ void gload_lds16(const void* g, void* l) {
    auto gp = (const __attribute__((address_space(1))) unsigned int*)(unsigned long long)(uintptr_t)g;
    auto lp = (__attribute__((address_space(3))) unsigned int*)(unsigned int)(uintptr_t)l;
    __builtin_amdgcn_global_load_lds(gp, lp, 16, 0, 0);
}

// ---------- exact-GELU with fast erf (A&S 7.1.26, |err|<=1.5e-7) -----------
// Validated R12-R17 (absmax 0.5). ~15 VALU ops vs libm erff ~84.
__device__ __forceinline__ float gelu_fast(float f) {
    const float z = f * 0.70710678118654752f;
    const float az = fabsf(z);
    const float t = __builtin_amdgcn_rcpf(fmaf(0.3275911f, az, 1.0f));
    float poly = fmaf(1.061405429f, t, -1.453152027f);
    poly = fmaf(poly, t, 1.421413741f);
    poly = fmaf(poly, t, -0.284496736f);
    poly = fmaf(poly, t, 0.254829592f);
    poly *= t;
    const float e = __builtin_amdgcn_exp2f(-az * az * 1.44269504088896f);
    float erfv = fmaf(-poly, e, 1.0f);
    erfv = copysignf(erfv, z);
    return 0.5f * f * (1.0f + erfv);
}

// ---------- prep A: W partial sums (80 blks) + x->bf16 cvt (7680 blks) ------
__global__ void prep_a(const float* __restrict__ x, __bf16* __restrict__ xb,
                       const float* __restrict__ W1, const float* __restrict__ W2,
                       float* __restrict__ partials, int epg1, int epg2,
                       unsigned int* __restrict__ gzero) {
    const int blk = blockIdx.x, tid = threadIdx.x;
    if (blk < 80) {
        const int y = blk >> 3, b = blk & 7;
        if (blk == 0 && tid < 16) gzero[tid] = 0u;
        const int epg = (y < 5) ? epg1 : epg2;
        const float* Wg = (y < 5) ? (W1 + (size_t)y * epg1)
                                  : (W2 + (size_t)(y - 5) * epg2);
        const int chunk4 = epg / (4 * NB);
        const float* base = Wg + (size_t)b * chunk4 * 4;
        float s = 0.f;
        for (int i = tid; i < chunk4; i += THREADS) {
            f32x4 v = *reinterpret_cast<const f32x4*>(base + 4 * (size_t)i);
            s += (v[0] + v[1]) + (v[2] + v[3]);
        }
        __shared__ float red[THREADS];
        red[tid] = s;
        __syncthreads();
        for (int off = THREADS / 2; off > 0; off >>= 1) {
            if (tid < off) red[tid] += red[tid + off];
            __syncthreads();
        }
        if (tid == 0) partials[y * NB + b] = red[0];
        return;
    }
    const int i = (blk - 80) * THREADS + tid;
    f32x4 v = *reinterpret_cast<const f32x4*>(x + 4 * (size_t)i);
    bf16x4 o;
    o[0] = (__bf16)v[0]; o[1] = (__bf16)v[1];
    o[2] = (__bf16)v[2]; o[3] = (__bf16)v[3];
    *reinterpret_cast<bf16x4*>(xb + 4 * (size_t)i) = o;
}

// ---------- prep B: binarize W1/W2 chunks + tail zero (82 blocks) -----------
__global__ void prep_b(const float* __restrict__ W1, __bf16* __restrict__ W1b,
                       const float* __restrict__ W2, __bf16* __restrict__ W2b,
                       const float* __restrict__ psums,
                       int epg1, int tail1, int epg2, int tail2) {
    int r = blockIdx.x;
    const int tid = threadIdx.x;
    const float* W; __bf16* Wb; const float* ps; int epg, tail;
    if (r <= 40) { W = W1; Wb = W1b; ps = psums;      epg = epg1; tail = tail1; }
    else { r -= 41; W = W2; Wb = W2b; ps = psums + 40; epg = epg2; tail = tail2; }
    if (r == 40) {
        __bf16* og = Wb + (size_t)5 * epg;
        for (int i = tid; i < tail; i += THREADS) og[i] = (__bf16)0.f;
        return;
    }
    const int g = r >> 3, b = r & 7;
    float total = 0.f;
#pragma unroll
    for (int j = 0; j < NB; ++j) total += ps[g * NB + j];
    const float mean = total / (float)epg;
    const int chunk4 = epg / (4 * NB);
    const size_t off0 = (size_t)g * epg + (size_t)b * chunk4 * 4;
    const float* base = W + off0;
    __bf16* ob = Wb + off0;
    for (int i = tid; i < chunk4; i += THREADS) {
        f32x4 v = *reinterpret_cast<const f32x4*>(base + 4 * (size_t)i);
        bf16x4 o;
#pragma unroll
        for (int j = 0; j < 4; ++j) {
            const float z = v[j] - mean;
            o[j] = (__bf16)((z > 0.f) ? 1.f : ((z < 0.f) ? -1.f : 0.f));
        }
        *reinterpret_cast<bf16x4*>(ob + 4 * (size_t)i) = o;
    }
}

// ========== 16-wave GEMM (4 waves/SIMD): Y[m,n] = A[m,:]*Bw[n,:] + bias[n] ==
// R16 structure with ONE variable changed: 1024 threads = 16 waves (4Mx4N),
// wave tile 64 x (BN_/4) -> 4 waves/SIMD (every prior variant ran at 2 —
// the shared constant across 7 falsified stall theories; all resources sat
// at ~20%, the latency-bound-with-low-concurrency signature). Per-thread
// acc halves to [4][NF] (64 f32) so VGPR fits 128/wave at 4 waves/SIMD.
// Proven pieces unchanged: 2-phase prefetch, gload_lds, T2 XOR swizzle,
// XCD bijective swizzle, SWAPPED mfma(bfv,af) -> packed wide stores.
template<int BN_, int OUT_BF16>
__global__ __launch_bounds__(1024, 1)
void gemm_w16(const __bf16* __restrict__ A, const __bf16* __restrict__ Bw,
              const float* __restrict__ bias, void* __restrict__ outp,
              unsigned int* __restrict__ gmax, int M, int N, int K,
              int GN, int nwg) {
    constexpr int BM = 256, BK = 64;
    constexpr int NF = BN_ / 64;               // 4 | 2
    constexpr int ABYTES = BM * BK * 2;        // 32768
    constexpr int BBYTES = BN_ * BK * 2;       // 32768 | 16384
    constexpr int AR = ABYTES / (1024 * 16);   // 2
    constexpr int BR = BBYTES / (1024 * 16);   // 2 | 1
    __shared__ __attribute__((aligned(16))) char lds[2 * (ABYTES + BBYTES)];

    const int tid = threadIdx.x;
    const int wave = tid >> 6, lane = tid & 63;
    const int l15 = lane & 15, l4 = lane >> 4;
    const int wr = wave >> 2, wc = wave & 3;   // 4x4 wave grid

    const int cpx = nwg >> 3;
    const int orig = (blockIdx.x & 7) * cpx + (blockIdx.x >> 3);
    const int bm = orig / GN, bn = orig % GN;

    const __bf16* Ab = A + (size_t)bm * BM * K;
    const __bf16* Bb = Bw + (size_t)bn * BN_ * K;
    const int NT = K / BK;

    f32x4 acc[4][NF];
#pragma unroll
    for (int m = 0; m < 4; ++m)
#pragma unroll
        for (int n = 0; n < NF; ++n)
            acc[m][n] = f32x4{0.f, 0.f, 0.f, 0.f};

    auto STAGE = [&](int t) {
        const int k0 = t * BK;
        char* ab = lds + (t & 1) * (ABYTES + BBYTES);
        char* bb = ab + ABYTES;
#pragma unroll
        for (int j = 0; j < AR; ++j) {
            const int q = j * 16384 + tid * 16;
            const int lr = q >> 7;
            const int s = ((q >> 4) & 7) ^ (lr & 7);
            gload_lds16(Ab + (size_t)lr * K + k0 + s * 8, ab + q);
        }
#pragma unroll
        for (int j = 0; j < BR; ++j) {
            const int q = j * 16384 + tid * 16;
            const int lr = q >> 7;
            const int s = ((q >> 4) & 7) ^ (lr & 7);
            gload_lds16(Bb + (size_t)lr * K + k0 + s * 8, bb + q);
        }
    };

    STAGE(0);
    asm volatile("s_waitcnt vmcnt(0)" ::: "memory");
    __syncthreads();

    for (int t = 0; t < NT; ++t) {
        if (t + 1 < NT) STAGE(t + 1);          // prefetch before compute
        const char* ab = lds + (t & 1) * (ABYTES + BBYTES);
        const char* bb = ab + ABYTES;
#pragma unroll
        for (int kk = 0; kk < 2; ++kk) {
            bf16x8 af[4], bfv[NF];
#pragma unroll
            for (int m = 0; m < 4; ++m) {
                const int r = wr * 64 + m * 16 + l15;
                const int sp = (kk * 4 + l4) ^ (r & 7);
                af[m] = *reinterpret_cast<const bf16x8*>(ab + r * 128 + sp * 16);
            }
#pragma unroll
            for (int n = 0; n < NF; ++n) {
                const int r = wc * (BN_ / 4) + n * 16 + l15;
                const int sp = (kk * 4 + l4) ^ (r & 7);
                bfv[n] = *reinterpret_cast<const bf16x8*>(bb + r * 128 + sp * 16);
            }
#pragma unroll
            for (int m = 0; m < 4; ++m)
#pragma unroll
                for (int n = 0; n < NF; ++n)
                    acc[m][n] = __builtin_amdgcn_mfma_f32_16x16x32_bf16(
                        bfv[n], af[m], acc[m][n], 0, 0, 0);   // SWAPPED
        }
        asm volatile("s_waitcnt vmcnt(0)" ::: "memory");
        __syncthreads();
    }

    // epilogue (swapped): row = rowb+m*16+l15, col = colb+n*16+l4*4+r
    const int rowb = bm * BM + wr * 64;
    const int colb = bn * BN_ + wc * (BN_ / 4);
    float lmax = 0.f;
#pragma unroll
    for (int n = 0; n < NF; ++n) {
        const f32x4 bv = *reinterpret_cast<const f32x4*>(bias + colb + n * 16 + l4 * 4);
#pragma unroll
        for (int m = 0; m < 4; ++m) {
            const int row = rowb + m * 16 + l15;
            if (OUT_BF16) {
                bf16x4 o;
#pragma unroll
                for (int r = 0; r < 4; ++r) {
                    const float v = acc[m][n][r] + bv[r];
                    lmax = fmaxf(lmax, fabsf(v));
                    o[r] = (__bf16)v;
                }
                *reinterpret_cast<bf16x4*>(
                    &((__bf16*)outp)[(size_t)row * N + colb + n * 16 + l4 * 4]) = o;
            } else {
                f32x4 o;
#pragma unroll
                for (int r = 0; r < 4; ++r) {
                    o[r] = acc[m][n][r] + bv[r];
                    lmax = fmaxf(lmax, fabsf(o[r]));
                }
                *reinterpret_cast<f32x4*>(
                    &((float*)outp)[(size_t)row * N + colb + n * 16 + l4 * 4]) = o;
            }
        }
    }
#pragma unroll
    for (int off = 32; off > 0; off >>= 1)
        lmax = fmaxf(lmax, __shfl_down(lmax, off, 64));
    float* wredmax = (float*)lds;   // safe: all tile reads done
    if (lane == 0) wredmax[wave] = lmax;
    __syncthreads();
    if (tid == 0) {
        float bmax = wredmax[0];
#pragma unroll
        for (int w = 1; w < 16; ++w) bmax = fmaxf(bmax, wredmax[w]);
        atomicMax(gmax + (bm * BM) / 4096, __float_as_uint(bmax));
    }
}

// ---------- in-place absmax quantize + FAST exact-GELU, grid-stride ---------
__global__ void quant_gelu(__bf16* __restrict__ y, const unsigned int* __restrict__ gbits,
                           int perg8, int n8) {
    const int stride = gridDim.x * blockDim.x;
    for (int i = blockIdx.x * blockDim.x + threadIdx.x; i < n8; i += stride) {
        const int g = i / perg8;
        const float gamma = __uint_as_float(gbits[g]);
        const float s = 128.0f / (gamma + 1e-5f);
        bf16x8 v = *reinterpret_cast<const bf16x8*>(y + 8 * (size_t)i);
        bf16x8 o;
#pragma unroll
        for (int j = 0; j < 8; ++j) {
            float f = (float)v[j] * s;
            f = fminf(fmaxf(f, -128.0f + 1e-5f), 128.0f - 1e-5f);
            o[j] = (__bf16)gelu_fast(f);
        }
        *reinterpret_cast<bf16x8*>(y + 8 * (size_t)i) = o;
    }
}

// ---------- in-place absmax quantize of f32 output ----------
__global__ void final_scale(float* __restrict__ y, const unsigned int* __restrict__ gbits,
                            int perg4, int n4) {
    int i = blockIdx.x * blockDim.x + threadIdx.x;
    if (i >= n4) return;
    const int g = i / perg4;
    const float gamma = __uint_as_float(gbits[g]);
    const float s = 128.0f / (gamma + 1e-5f);
    f32x4 v = *reinterpret_cast<const f32x4*>(y + 4 * (size_t)i);
    f32x4 o;
#pragma unroll
    for (int j = 0; j < 4; ++j)
        o[j] = fminf(fmaxf(v[j] * s, -128.0f + 1e-5f), 128.0f - 1e-5f);
    *reinterpret_cast<f32x4*>(y + 4 * (size_t)i) = o;
}

extern "C" void kernel_launch(void* const* d_in, const int* in_sizes, int n_in,
                              void* d_out, int out_size, void* d_ws, size_t ws_size,
                              hipStream_t stream) {
    const float* x  = (const float*)d_in[0];   // (10,2048,384)
    const float* W1 = (const float*)d_in[1];   // (1536,384)
    const float* b1 = (const float*)d_in[2];   // (1536,)
    const float* W2 = (const float*)d_in[3];   // (384,1536)
    const float* b2 = (const float*)d_in[4];   // (384,)
    float* out = (float*)d_out;                // (10,2048,384) f32

    const int BB = 10, TT = 2048, C = 384, H = 1536;
    const int M = BB * TT;                     // 20480; act group = 4096 rows

    const int gs1 = H / 5;                     // 307
    const int gs2 = C / 5;                     // 76
    const int epg1 = gs1 * C;                  // 117888
    const int epg2 = gs2 * H;                  // 116736
    const int tail1 = (H - 5 * gs1) * C;       // 384
    const int tail2 = (C - 5 * gs2) * H;       // 6144

    const size_t szW1b = (size_t)H * C * 2;
    const size_t szW2b = (size_t)C * H * 2;
    const size_t szXb  = (size_t)M * C * 2;
    const size_t szY1  = (size_t)M * H * 2;

    char* p = (char*)d_ws;
    __bf16* W1b = (__bf16*)p; p += szW1b;
    __bf16* W2b = (__bf16*)p; p += szW2b;
    __bf16* xb  = (__bf16*)p; p += szXb;
    __bf16* y1  = (__bf16*)p; p += szY1;
    unsigned int* gamma = (unsigned int*)p; p += 64;
    float* psums = (float*)p; p += 2 * 5 * NB * 4;
    if ((size_t)(p - (char*)d_ws) > ws_size) return;

    // 1) W partial sums (80 blks, gamma zero) + x->bf16 cvt (7680 blks)
    prep_a<<<7760, THREADS, 0, stream>>>(x, xb, W1, W2, psums, epg1, epg2, gamma);

    // 2) binarize W1/W2 + tail zeroing
    prep_b<<<82, THREADS, 0, stream>>>(W1, W1b, W2, W2b, psums,
                                       epg1, tail1, epg2, tail2);

    // 3) GEMM1: 20480x1536x384, BM=256 BN=256, 16 waves. grid 80*6 = 480
    gemm_w16<256, 1><<<480, 1024, 0, stream>>>(
        xb, W1b, b1, (void*)y1, gamma, M, H, C, H / 256, 480);

    // 4) quant+gelu (fast erf), grid-stride
    quant_gelu<<<2048, THREADS, 0, stream>>>(
        y1, gamma, (M / 5) * H / 8, M * H / 8);

    // 5) GEMM2: 20480x384x1536, BM=256 BN=128, 16 waves. grid 80*3 = 240
    gemm_w16<128, 0><<<240, 1024, 0, stream>>>(
        y1, W2b, b2, (void*)out, gamma + 5, M, C, H, C / 128, 240);

    // 6) final scale+clip of output
    final_scale<<<(M * C / 4 + THREADS - 1) / THREADS, THREADS, 0, stream>>>(
        out, gamma + 5, (M / 5) * C / 4, M * C / 4);
}

// Round 19
// 130.468 us; speedup vs baseline: 1.0653x; 1.0025x over previous
//
#include <hip/hip_runtime.h>
#include <cstdint>
#include <cstddef>

#define THREADS 256
#define NB 8   // partial-sum blocks per group

typedef float f32x4 __attribute__((ext_vector_type(4)));
typedef __bf16 bf16x8 __attribute__((ext_vector_type(8)));
typedef __bf16 bf16x4 __attribute__((ext_vector_type(4)));

// ---------- async global->LDS, 16B per lane, wave-uniform LDS base ----------
__device__ __forceinline__ void gload_lds16(const void* g, void* l) {
    auto gp = (const __attribute__((address_space(1))) unsigned int*)(unsigned long long)(uintptr_t)g;
    auto lp = (__attribute__((address_space(3))) unsigned int*)(unsigned int)(uintptr_t)l;
    __builtin_amdgcn_global_load_lds(gp, lp, 16, 0, 0);
}

// ---------- exact-GELU with fast erf (A&S 7.1.26, |err|<=1.5e-7) -----------
// Validated R12-R17 (absmax 0.5). ~15 VALU ops vs libm erff ~84.
__device__ __forceinline__ float gelu_fast(float f) {
    const float z = f * 0.70710678118654752f;
    const float az = fabsf(z);
    const float t = __builtin_amdgcn_rcpf(fmaf(0.3275911f, az, 1.0f));
    float poly = fmaf(1.061405429f, t, -1.453152027f);
    poly = fmaf(poly, t, 1.421413741f);
    poly = fmaf(poly, t, -0.284496736f);
    poly = fmaf(poly, t, 0.254829592f);
    poly *= t;
    const float e = __builtin_amdgcn_exp2f(-az * az * 1.44269504088896f);
    float erfv = fmaf(-poly, e, 1.0f);
    erfv = copysignf(erfv, z);
    return 0.5f * f * (1.0f + erfv);
}

// ---------- prep A: W partial sums (80 blks) + x->bf16 cvt (7680 blks) ------
__global__ void prep_a(const float* __restrict__ x, __bf16* __restrict__ xb,
                       const float* __restrict__ W1, const float* __restrict__ W2,
                       float* __restrict__ partials, int epg1, int epg2,
                       unsigned int* __restrict__ gzero) {
    const int blk = blockIdx.x, tid = threadIdx.x;
    if (blk < 80) {
        const int y = blk >> 3, b = blk & 7;
        if (blk == 0 && tid < 16) gzero[tid] = 0u;
        const int epg = (y < 5) ? epg1 : epg2;
        const float* Wg = (y < 5) ? (W1 + (size_t)y * epg1)
                                  : (W2 + (size_t)(y - 5) * epg2);
        const int chunk4 = epg / (4 * NB);
        const float* base = Wg + (size_t)b * chunk4 * 4;
        float s = 0.f;
        for (int i = tid; i < chunk4; i += THREADS) {
            f32x4 v = *reinterpret_cast<const f32x4*>(base + 4 * (size_t)i);
            s += (v[0] + v[1]) + (v[2] + v[3]);
        }
        __shared__ float red[THREADS];
        red[tid] = s;
        __syncthreads();
        for (int off = THREADS / 2; off > 0; off >>= 1) {
            if (tid < off) red[tid] += red[tid + off];
            __syncthreads();
        }
        if (tid == 0) partials[y * NB + b] = red[0];
        return;
    }
    const int i = (blk - 80) * THREADS + tid;
    f32x4 v = *reinterpret_cast<const f32x4*>(x + 4 * (size_t)i);
    bf16x4 o;
    o[0] = (__bf16)v[0]; o[1] = (__bf16)v[1];
    o[2] = (__bf16)v[2]; o[3] = (__bf16)v[3];
    *reinterpret_cast<bf16x4*>(xb + 4 * (size_t)i) = o;
}

// ---------- prep B: binarize W1/W2 chunks + tail zero (82 blocks) -----------
__global__ void prep_b(const float* __restrict__ W1, __bf16* __restrict__ W1b,
                       const float* __restrict__ W2, __bf16* __restrict__ W2b,
                       const float* __restrict__ psums,
                       int epg1, int tail1, int epg2, int tail2) {
    int r = blockIdx.x;
    const int tid = threadIdx.x;
    const float* W; __bf16* Wb; const float* ps; int epg, tail;
    if (r <= 40) { W = W1; Wb = W1b; ps = psums;      epg = epg1; tail = tail1; }
    else { r -= 41; W = W2; Wb = W2b; ps = psums + 40; epg = epg2; tail = tail2; }
    if (r == 40) {
        __bf16* og = Wb + (size_t)5 * epg;
        for (int i = tid; i < tail; i += THREADS) og[i] = (__bf16)0.f;
        return;
    }
    const int g = r >> 3, b = r & 7;
    float total = 0.f;
#pragma unroll
    for (int j = 0; j < NB; ++j) total += ps[g * NB + j];
    const float mean = total / (float)epg;
    const int chunk4 = epg / (4 * NB);
    const size_t off0 = (size_t)g * epg + (size_t)b * chunk4 * 4;
    const float* base = W + off0;
    __bf16* ob = Wb + off0;
    for (int i = tid; i < chunk4; i += THREADS) {
        f32x4 v = *reinterpret_cast<const f32x4*>(base + 4 * (size_t)i);
        bf16x4 o;
#pragma unroll
        for (int j = 0; j < 4; ++j) {
            const float z = v[j] - mean;
            o[j] = (__bf16)((z > 0.f) ? 1.f : ((z < 0.f) ? -1.f : 0.f));
        }
        *reinterpret_cast<bf16x4*>(ob + 4 * (size_t)i) = o;
    }
}

// ========== 16-wave GEMM (4 waves/SIMD): Y[m,n] = A[m,:]*Bw[n,:] + bias[n] ==
// R16 structure with ONE variable changed: 1024 threads = 16 waves (4Mx4N),
// wave tile 64 x (BN_/4) -> 4 waves/SIMD (every prior variant ran at 2 —
// the shared constant across 7 falsified stall theories; all resources sat
// at ~20%, the latency-bound-with-low-concurrency signature). Per-thread
// acc halves to [4][NF] (64 f32) so VGPR fits 128/wave at 4 waves/SIMD.
// Proven pieces unchanged: 2-phase prefetch, gload_lds, T2 XOR swizzle,
// XCD bijective swizzle, SWAPPED mfma(bfv,af) -> packed wide stores.
template<int BN_, int OUT_BF16>
__global__ __launch_bounds__(1024, 1)
void gemm_w16(const __bf16* __restrict__ A, const __bf16* __restrict__ Bw,
              const float* __restrict__ bias, void* __restrict__ outp,
              unsigned int* __restrict__ gmax, int M, int N, int K,
              int GN, int nwg) {
    constexpr int BM = 256, BK = 64;
    constexpr int NF = BN_ / 64;               // 4 | 2
    constexpr int ABYTES = BM * BK * 2;        // 32768
    constexpr int BBYTES = BN_ * BK * 2;       // 32768 | 16384
    constexpr int AR = ABYTES / (1024 * 16);   // 2
    constexpr int BR = BBYTES / (1024 * 16);   // 2 | 1
    __shared__ __attribute__((aligned(16))) char lds[2 * (ABYTES + BBYTES)];

    const int tid = threadIdx.x;
    const int wave = tid >> 6, lane = tid & 63;
    const int l15 = lane & 15, l4 = lane >> 4;
    const int wr = wave >> 2, wc = wave & 3;   // 4x4 wave grid

    const int cpx = nwg >> 3;
    const int orig = (blockIdx.x & 7) * cpx + (blockIdx.x >> 3);
    const int bm = orig / GN, bn = orig % GN;

    const __bf16* Ab = A + (size_t)bm * BM * K;
    const __bf16* Bb = Bw + (size_t)bn * BN_ * K;
    const int NT = K / BK;

    f32x4 acc[4][NF];
#pragma unroll
    for (int m = 0; m < 4; ++m)
#pragma unroll
        for (int n = 0; n < NF; ++n)
            acc[m][n] = f32x4{0.f, 0.f, 0.f, 0.f};

    auto STAGE = [&](int t) {
        const int k0 = t * BK;
        char* ab = lds + (t & 1) * (ABYTES + BBYTES);
        char* bb = ab + ABYTES;
#pragma unroll
        for (int j = 0; j < AR; ++j) {
            const int q = j * 16384 + tid * 16;
            const int lr = q >> 7;
            const int s = ((q >> 4) & 7) ^ (lr & 7);
            gload_lds16(Ab + (size_t)lr * K + k0 + s * 8, ab + q);
        }
#pragma unroll
        for (int j = 0; j < BR; ++j) {
            const int q = j * 16384 + tid * 16;
            const int lr = q >> 7;
            const int s = ((q >> 4) & 7) ^ (lr & 7);
            gload_lds16(Bb + (size_t)lr * K + k0 + s * 8, bb + q);
        }
    };

    STAGE(0);
    asm volatile("s_waitcnt vmcnt(0)" ::: "memory");
    __syncthreads();

    for (int t = 0; t < NT; ++t) {
        if (t + 1 < NT) STAGE(t + 1);          // prefetch before compute
        const char* ab = lds + (t & 1) * (ABYTES + BBYTES);
        const char* bb = ab + ABYTES;
#pragma unroll
        for (int kk = 0; kk < 2; ++kk) {
            bf16x8 af[4], bfv[NF];
#pragma unroll
            for (int m = 0; m < 4; ++m) {
                const int r = wr * 64 + m * 16 + l15;
                const int sp = (kk * 4 + l4) ^ (r & 7);
                af[m] = *reinterpret_cast<const bf16x8*>(ab + r * 128 + sp * 16);
            }
#pragma unroll
            for (int n = 0; n < NF; ++n) {
                const int r = wc * (BN_ / 4) + n * 16 + l15;
                const int sp = (kk * 4 + l4) ^ (r & 7);
                bfv[n] = *reinterpret_cast<const bf16x8*>(bb + r * 128 + sp * 16);
            }
#pragma unroll
            for (int m = 0; m < 4; ++m)
#pragma unroll
                for (int n = 0; n < NF; ++n)
                    acc[m][n] = __builtin_amdgcn_mfma_f32_16x16x32_bf16(
                        bfv[n], af[m], acc[m][n], 0, 0, 0);   // SWAPPED
        }
        asm volatile("s_waitcnt vmcnt(0)" ::: "memory");
        __syncthreads();
    }

    // epilogue (swapped): row = rowb+m*16+l15, col = colb+n*16+l4*4+r
    const int rowb = bm * BM + wr * 64;
    const int colb = bn * BN_ + wc * (BN_ / 4);
    float lmax = 0.f;
#pragma unroll
    for (int n = 0; n < NF; ++n) {
        const f32x4 bv = *reinterpret_cast<const f32x4*>(bias + colb + n * 16 + l4 * 4);
#pragma unroll
        for (int m = 0; m < 4; ++m) {
            const int row = rowb + m * 16 + l15;
            if (OUT_BF16) {
                bf16x4 o;
#pragma unroll
                for (int r = 0; r < 4; ++r) {
                    const float v = acc[m][n][r] + bv[r];
                    lmax = fmaxf(lmax, fabsf(v));
                    o[r] = (__bf16)v;
                }
                *reinterpret_cast<bf16x4*>(
                    &((__bf16*)outp)[(size_t)row * N + colb + n * 16 + l4 * 4]) = o;
            } else {
                f32x4 o;
#pragma unroll
                for (int r = 0; r < 4; ++r) {
                    o[r] = acc[m][n][r] + bv[r];
                    lmax = fmaxf(lmax, fabsf(o[r]));
                }
                *reinterpret_cast<f32x4*>(
                    &((float*)outp)[(size_t)row * N + colb + n * 16 + l4 * 4]) = o;
            }
        }
    }
#pragma unroll
    for (int off = 32; off > 0; off >>= 1)
        lmax = fmaxf(lmax, __shfl_down(lmax, off, 64));
    float* wredmax = (float*)lds;   // safe: all tile reads done
    if (lane == 0) wredmax[wave] = lmax;
    __syncthreads();
    if (tid == 0) {
        float bmax = wredmax[0];
#pragma unroll
        for (int w = 1; w < 16; ++w) bmax = fmaxf(bmax, wredmax[w]);
        atomicMax(gmax + (bm * BM) / 4096, __float_as_uint(bmax));
    }
}

// ---------- in-place absmax quantize + FAST exact-GELU, grid-stride ---------
__global__ void quant_gelu(__bf16* __restrict__ y, const unsigned int* __restrict__ gbits,
                           int perg8, int n8) {
    const int stride = gridDim.x * blockDim.x;
    for (int i = blockIdx.x * blockDim.x + threadIdx.x; i < n8; i += stride) {
        const int g = i / perg8;
        const float gamma = __uint_as_float(gbits[g]);
        const float s = 128.0f / (gamma + 1e-5f);
        bf16x8 v = *reinterpret_cast<const bf16x8*>(y + 8 * (size_t)i);
        bf16x8 o;
#pragma unroll
        for (int j = 0; j < 8; ++j) {
            float f = (float)v[j] * s;
            f = fminf(fmaxf(f, -128.0f + 1e-5f), 128.0f - 1e-5f);
            o[j] = (__bf16)gelu_fast(f);
        }
        *reinterpret_cast<bf16x8*>(y + 8 * (size_t)i) = o;
    }
}

// ---------- in-place absmax quantize of f32 output ----------
__global__ void final_scale(float* __restrict__ y, const unsigned int* __restrict__ gbits,
                            int perg4, int n4) {
    int i = blockIdx.x * blockDim.x + threadIdx.x;
    if (i >= n4) return;
    const int g = i / perg4;
    const float gamma = __uint_as_float(gbits[g]);
    const float s = 128.0f / (gamma + 1e-5f);
    f32x4 v = *reinterpret_cast<const f32x4*>(y + 4 * (size_t)i);
    f32x4 o;
#pragma unroll
    for (int j = 0; j < 4; ++j)
        o[j] = fminf(fmaxf(v[j] * s, -128.0f + 1e-5f), 128.0f - 1e-5f);
    *reinterpret_cast<f32x4*>(y + 4 * (size_t)i) = o;
}

extern "C" void kernel_launch(void* const* d_in, const int* in_sizes, int n_in,
                              void* d_out, int out_size, void* d_ws, size_t ws_size,
                              hipStream_t stream) {
    const float* x  = (const float*)d_in[0];   // (10,2048,384)
    const float* W1 = (const float*)d_in[1];   // (1536,384)
    const float* b1 = (const float*)d_in[2];   // (1536,)
    const float* W2 = (const float*)d_in[3];   // (384,1536)
    const float* b2 = (const float*)d_in[4];   // (384,)
    float* out = (float*)d_out;                // (10,2048,384) f32

    const int BB = 10, TT = 2048, C = 384, H = 1536;
    const int M = BB * TT;                     // 20480; act group = 4096 rows

    const int gs1 = H / 5;                     // 307
    const int gs2 = C / 5;                     // 76
    const int epg1 = gs1 * C;                  // 117888
    const int epg2 = gs2 * H;                  // 116736
    const int tail1 = (H - 5 * gs1) * C;       // 384
    const int tail2 = (C - 5 * gs2) * H;       // 6144

    const size_t szW1b = (size_t)H * C * 2;
    const size_t szW2b = (size_t)C * H * 2;
    const size_t szXb  = (size_t)M * C * 2;
    const size_t szY1  = (size_t)M * H * 2;

    char* p = (char*)d_ws;
    __bf16* W1b = (__bf16*)p; p += szW1b;
    __bf16* W2b = (__bf16*)p; p += szW2b;
    __bf16* xb  = (__bf16*)p; p += szXb;
    __bf16* y1  = (__bf16*)p; p += szY1;
    unsigned int* gamma = (unsigned int*)p; p += 64;
    float* psums = (float*)p; p += 2 * 5 * NB * 4;
    if ((size_t)(p - (char*)d_ws) > ws_size) return;

    // 1) W partial sums (80 blks, gamma zero) + x->bf16 cvt (7680 blks)
    prep_a<<<7760, THREADS, 0, stream>>>(x, xb, W1, W2, psums, epg1, epg2, gamma);

    // 2) binarize W1/W2 + tail zeroing
    prep_b<<<82, THREADS, 0, stream>>>(W1, W1b, W2, W2b, psums,
                                       epg1, tail1, epg2, tail2);

    // 3) GEMM1: 20480x1536x384, BM=256 BN=256, 16 waves. grid 80*6 = 480
    gemm_w16<256, 1><<<480, 1024, 0, stream>>>(
        xb, W1b, b1, (void*)y1, gamma, M, H, C, H / 256, 480);

    // 4) quant+gelu (fast erf), grid-stride
    quant_gelu<<<2048, THREADS, 0, stream>>>(
        y1, gamma, (M / 5) * H / 8, M * H / 8);

    // 5) GEMM2: 20480x384x1536, BM=256 BN=128, 16 waves. grid 80*3 = 240
    gemm_w16<128, 0><<<240, 1024, 0, stream>>>(
        y1, W2b, b2, (void*)out, gamma + 5, M, C, H, C / 128, 240);

    // 6) final scale+clip of output
    final_scale<<<(M * C / 4 + THREADS - 1) / THREADS, THREADS, 0, stream>>>(
        out, gamma + 5, (M / 5) * C / 4, M * C / 4);
}